// Round 1
// baseline (134.556 us; speedup 1.0000x reference)
//
#include <hip/hip_runtime.h>
#include <math.h>

// Problem constants (from reference)
constexpr int   T_PTS  = 4096;
constexpr float LN2    = 0.69314718055994530942f;
// ct = param0 * 5/100 * (RO/KAV) * (1-HLV)/(1-HSV) * (-ln2/TE) * W
// scale applied at the end; keep factors separate to match ref rounding closely.

__global__ __launch_bounds__(256) void perfusion_row_reduce(
    const float* __restrict__ param,   // [N,3]
    const float* __restrict__ T10,     // [N,1]
    const float* __restrict__ cp,      // [N,T]
    float* __restrict__ out)           // [N,1]
{
    const int row = blockIdx.x;
    const int tid = threadIdx.x;

    const float* cprow = cp + (size_t)row * T_PTS;
    const float4* cpv  = (const float4*)cprow;

    // Each thread: 4 coalesced float4 loads = 16 elements
    float s = 0.0f;
#pragma unroll
    for (int it = 0; it < 4; ++it) {
        float4 v = cpv[it * 256 + tid];
        s += __log2f(v.x) + __log2f(v.y) + __log2f(v.z) + __log2f(v.w);
    }

    // Wave-level butterfly reduction (wave = 64 lanes on CDNA)
#pragma unroll
    for (int off = 32; off > 0; off >>= 1)
        s += __shfl_down(s, off, 64);

    __shared__ float ws[4];
    const int wave = tid >> 6;
    const int lane = tid & 63;
    if (lane == 0) ws[wave] = s;
    __syncthreads();

    if (tid == 0) {
        float S = ws[0] + ws[1] + ws[2] + ws[3];
        // trapezoid endpoint correction: subtract half of first+last sample
        float corr = 0.5f * (__log2f(cprow[0]) + __log2f(cprow[T_PTS - 1]));
        // W = sum_t w_t*log2(cp_t) - 4095*log2(T10)   (sum of weights = T-1)
        float W = S - corr - 4095.0f * __log2f(T10[row]);
        float integral = (-LN2 / 32.0f) * W;          // (-1/TE)*ln(...)  integrated
        float cbv = param[row * 3] * 5.0f;
        float ct = cbv / 100.0f * (1.04f / 1.4f) * ((1.0f - 0.45f) / (1.0f - 0.25f)) * integral;
        out[row] = ct;
    }
}

extern "C" void kernel_launch(void* const* d_in, const int* in_sizes, int n_in,
                              void* d_out, int out_size, void* d_ws, size_t ws_size,
                              hipStream_t stream) {
    const float* param = (const float*)d_in[0];  // [N,3]
    const float* T10   = (const float*)d_in[1];  // [N,1]
    const float* cp    = (const float*)d_in[2];  // [N,T]
    // d_in[3] = raw_s -- unused by the reference; never touched (saves 64 MB of traffic)
    float* out = (float*)d_out;                  // [N,1] float32

    const int N = in_sizes[1];                   // T10 has N elements
    perfusion_row_reduce<<<N, 256, 0, stream>>>(param, T10, cp, out);
}